// Round 1
// 1427.178 us; speedup vs baseline: 1.4383x; 1.4383x over previous
//
#include <hip/hip_runtime.h>
#include <hip/hip_bf16.h>
#include <cstdint>
#include <cstddef>

typedef unsigned short u16;
typedef __attribute__((ext_vector_type(8))) short bf16x8;   // MFMA A/B operand (8 bf16 in 4 VGPRs)
typedef __attribute__((ext_vector_type(4))) float f32x4;    // MFMA C/D operand
typedef __attribute__((ext_vector_type(8))) unsigned short u16x8;

__device__ inline u16 f2bf(float f) {
  union { float f; uint32_t u; } v; v.f = f;
  uint32_t r = v.u + 0x7fffu + ((v.u >> 16) & 1u);   // RNE
  return (u16)(r >> 16);
}

// ---------------------------------------------------------------------------
// fp32 -> bf16 streaming convert (8 elem/thread/iter, grid-stride).
// Removes the per-tile f2bf VALU from every GEMM staging loop (A was
// re-converted 8x, W 64x).
// ---------------------------------------------------------------------------
__global__ __launch_bounds__(256)
void cvt_bf16(const float* __restrict__ in, u16* __restrict__ out, int n8) {
  int idx = blockIdx.x * 256 + threadIdx.x;
  int stride = gridDim.x * 256;
  for (int i = idx; i < n8; i += stride) {
    float4 a = ((const float4*)in)[i * 2];
    float4 b = ((const float4*)in)[i * 2 + 1];
    u16x8 v = { f2bf(a.x), f2bf(a.y), f2bf(a.z), f2bf(a.w),
                f2bf(b.x), f2bf(b.y), f2bf(b.z), f2bf(b.w) };
    ((u16x8*)out)[i] = v;
  }
}

// ---------------------------------------------------------------------------
// C[m,n] = sum_k A[m,k] * W[n,k] + bias[n]   (torch Linear: x @ W.T + b)
// A,W bf16 row-major [.,1024]. Tile 128x128, BK=64, 4 waves (64x64 quadrant).
// Register-prefetch (T14): next K-tile's global loads issue during MFMA.
// ---------------------------------------------------------------------------
template<bool OUT_F32>
__global__ __launch_bounds__(256, 3)
void gemm_bt(const u16* __restrict__ A, const u16* __restrict__ W,
             const float* __restrict__ bias, void* __restrict__ Cout) {
  const int K = 1024, N = 1024;
  const int m0 = blockIdx.y * 128, n0 = blockIdx.x * 128;
  __shared__ u16 As[128][72];   // +8 pad: row stride 144B keeps bank aliasing 2-way (free)
  __shared__ u16 Bs[128][72];
  const int tid  = threadIdx.x;
  const int wave = tid >> 6, lane = tid & 63;
  const int quad = lane >> 4, l16 = lane & 15;
  const int wr = (wave >> 1) * 64, wc = (wave & 1) * 64;

  const u16* Arow = A + (size_t)m0 * K;
  const u16* Wrow = W + (size_t)n0 * K;

  f32x4 acc[4][4] = {};
  u16x8 ap[4], bp[4];
#pragma unroll
  for (int t = 0; t < 4; t++) {            // 128 rows x 8 chunks(8 bf16) each mat
    int c = tid + t * 256, row = c >> 3, col = (c & 7) * 8;
    ap[t] = *(const u16x8*)(Arow + (size_t)row * K + col);
    bp[t] = *(const u16x8*)(Wrow + (size_t)row * K + col);
  }

  for (int k0 = 0; k0 < K; k0 += 64) {
    __syncthreads();                       // prev tile's fragment readers done
#pragma unroll
    for (int t = 0; t < 4; t++) {
      int c = tid + t * 256, row = c >> 3, col = (c & 7) * 8;
      *(u16x8*)&As[row][col] = ap[t];
      *(u16x8*)&Bs[row][col] = bp[t];
    }
    __syncthreads();
    if (k0 + 64 < K) {                     // prefetch next tile into regs
#pragma unroll
      for (int t = 0; t < 4; t++) {
        int c = tid + t * 256, row = c >> 3, col = (c & 7) * 8;
        ap[t] = *(const u16x8*)(Arow + (size_t)row * K + k0 + 64 + col);
        bp[t] = *(const u16x8*)(Wrow + (size_t)row * K + k0 + 64 + col);
      }
    }
#pragma unroll
    for (int ks = 0; ks < 2; ks++) {
      bf16x8 af[4], bg[4];
#pragma unroll
      for (int i = 0; i < 4; i++)
        af[i] = *(const bf16x8*)&As[wr + i * 16 + l16][ks * 32 + quad * 8];
#pragma unroll
      for (int j = 0; j < 4; j++)
        bg[j] = *(const bf16x8*)&Bs[wc + j * 16 + l16][ks * 32 + quad * 8];
#pragma unroll
      for (int i = 0; i < 4; i++)
#pragma unroll
        for (int j = 0; j < 4; j++)
          acc[i][j] = __builtin_amdgcn_mfma_f32_16x16x32_bf16(af[i], bg[j], acc[i][j], 0, 0, 0);
    }
  }

  // epilogue: C/D layout row = quad*4 + r, col = l16
#pragma unroll
  for (int i = 0; i < 4; i++)
#pragma unroll
    for (int j = 0; j < 4; j++) {
      int col = n0 + wc + j * 16 + l16;
      float bv = bias[col];
#pragma unroll
      for (int r = 0; r < 4; r++) {
        int row = m0 + wr + i * 16 + quad * 4 + r;
        float v = acc[i][j][r] + bv;
        if constexpr (OUT_F32) ((float*)Cout)[(size_t)row * N + col] = v;
        else                   ((u16*)Cout)[(size_t)row * N + col]   = f2bf(v);
      }
    }
}

// ---------------------------------------------------------------------------
// Vp [b*2048+kk][h*64+d] bf16  ->  Vt [bh][d][kk=2048] bf16  (per-head transpose)
// ---------------------------------------------------------------------------
__global__ __launch_bounds__(256)
void transpose_v(const u16* __restrict__ Vp, u16* __restrict__ Vt) {
  const int bh = blockIdx.y, b = bh >> 4, h = bh & 15;
  const int kk0 = blockIdx.x * 64;
  __shared__ u16 t[64][72];
  const int tid = threadIdx.x;
  for (int c = tid; c < 512; c += 256) {       // 64 kk rows x 8 chunks(8 d)
    int kk = c >> 3, d8 = c & 7;
    *(u16x8*)&t[kk][d8 * 8] =
        *(const u16x8*)(Vp + (size_t)(b * 2048 + kk0 + kk) * 1024 + h * 64 + d8 * 8);
  }
  __syncthreads();
  for (int c = tid; c < 512; c += 256) {       // 64 d rows x 8 chunks(8 kk)
    int d = c >> 3, k8 = c & 7;
    u16x8 v;
#pragma unroll
    for (int j = 0; j < 8; j++) v[j] = t[k8 * 8 + j][d];
    *(u16x8*)(Vt + ((size_t)bh * 64 + d) * 2048 + kk0 + k8 * 8) = v;
  }
}

// ---------------------------------------------------------------------------
// Fused attention per (bh, q-tile of 128): two passes over K-tiles of 64.
// v2 changes vs previous session:
//  - 1D grid with XCD-bijective remap: all 16 q-tiles of one head land on one
//    XCD -> K/V slice is L2-resident per XCD.
//  - Q fragments hoisted to registers once; Qs LDS reused as Ws -> LDS 37.4KB
//    -> 3 blocks/CU (launch_bounds(256,3)) vs 2 before.
//  - T14 register-prefetch of next K(/V) tile during compute.
//  - Ws is wave-private (each wave writes/reads only its own 32 rows):
//    the barrier between Ws-write and PV is replaced by s_waitcnt lgkmcnt(0).
// ---------------------------------------------------------------------------
__global__ __launch_bounds__(256, 3)
void attn(const u16* __restrict__ Qp, const u16* __restrict__ Kp,
          const u16* __restrict__ Vt, float* __restrict__ attw,
          u16* __restrict__ AO) {
  const int dlin = blockIdx.x;                  // 1024 blocks, 1D
  const int bh = (dlin & 7) + ((dlin >> 7) << 3);   // XCD x serves heads x, x+8, ...
  const int qt = (dlin >> 3) & 15;
  const int b = bh >> 4, h = bh & 15;
  const int q0 = qt * 128;
  const float scale = 0.125f;     // 1/sqrt(64)

  __shared__ u16 QW[128][72];     // Q tile, then reused as Ws (weights)
  __shared__ u16 Ks[64][72];      // kk x d
  __shared__ u16 Vs[64][72];      // d x kk   (from pre-transposed Vt)
  __shared__ float lsum[128];

  const int tid  = threadIdx.x;
  const int wave = tid >> 6, lane = tid & 63;
  const int quad = lane >> 4, l16 = lane & 15;

  // stage Q tile, hoist this wave's fragments into registers
  for (int c = tid; c < 1024; c += 256) {
    int row = c >> 3, c8 = c & 7;
    *(u16x8*)&QW[row][c8 * 8] =
        *(const u16x8*)(Qp + (size_t)(b * 2048 + q0 + row) * 1024 + h * 64 + c8 * 8);
  }
  __syncthreads();
  bf16x8 qf[2][2];
#pragma unroll
  for (int i = 0; i < 2; i++)
#pragma unroll
    for (int ks = 0; ks < 2; ks++)
      qf[i][ks] = *(const bf16x8*)&QW[wave * 32 + i * 16 + l16][ks * 32 + quad * 8];
  // QW is dead as Q from here (all waves' frags hoisted before any Ws write,
  // which first happens in pass 2, many barriers later).

  const u16* Kb = Kp + (size_t)b * 2048 * 1024 + h * 64;   // + kk*1024
  const u16* Vb = Vt + (size_t)bh * 64 * 2048;             // + d*2048
  const int sr0 = tid >> 3, sc0 = (tid & 7) * 8;           // staging chunk rows 0..31
  const int sr1 = sr0 + 32;                                // rows 32..63

  float es[2][4] = {};            // per-lane exp-sum partials [row-tile][r]

  // ---------------- pass 1: row sums ----------------
  u16x8 kp0 = *(const u16x8*)(Kb + (size_t)sr0 * 1024 + sc0);
  u16x8 kp1 = *(const u16x8*)(Kb + (size_t)sr1 * 1024 + sc0);
  for (int kt = 0; kt < 2048; kt += 64) {
    __syncthreads();                       // prev tile's Ks readers done
    *(u16x8*)&Ks[sr0][sc0] = kp0;
    *(u16x8*)&Ks[sr1][sc0] = kp1;
    __syncthreads();
    if (kt + 64 < 2048) {                  // prefetch next K tile into regs
      kp0 = *(const u16x8*)(Kb + (size_t)(kt + 64 + sr0) * 1024 + sc0);
      kp1 = *(const u16x8*)(Kb + (size_t)(kt + 64 + sr1) * 1024 + sc0);
    }
    f32x4 acc[2][4] = {};
#pragma unroll
    for (int ks = 0; ks < 2; ks++) {
      bf16x8 bg[4];
#pragma unroll
      for (int j = 0; j < 4; j++)
        bg[j] = *(const bf16x8*)&Ks[j * 16 + l16][ks * 32 + quad * 8];
#pragma unroll
      for (int i = 0; i < 2; i++)
#pragma unroll
        for (int j = 0; j < 4; j++)
          acc[i][j] = __builtin_amdgcn_mfma_f32_16x16x32_bf16(qf[i][ks], bg[j], acc[i][j], 0, 0, 0);
    }
#pragma unroll
    for (int i = 0; i < 2; i++)
#pragma unroll
      for (int j = 0; j < 4; j++)
#pragma unroll
        for (int r = 0; r < 4; r++)
          es[i][r] += __expf(acc[i][j][r] * scale);
  }
  // reduce across the 16 lanes of each quad (each quad owns rows quad*4+r)
#pragma unroll
  for (int off = 1; off < 16; off <<= 1)
#pragma unroll
    for (int i = 0; i < 2; i++)
#pragma unroll
      for (int r = 0; r < 4; r++)
        es[i][r] += __shfl_xor(es[i][r], off, 64);
  if (l16 == 0)
#pragma unroll
    for (int i = 0; i < 2; i++)
#pragma unroll
      for (int r = 0; r < 4; r++)
        lsum[wave * 32 + i * 16 + quad * 4 + r] = es[i][r];
  __syncthreads();
  float linv[2][4];
#pragma unroll
  for (int i = 0; i < 2; i++)
#pragma unroll
    for (int r = 0; r < 4; r++)
      linv[i][r] = 1.0f / lsum[wave * 32 + i * 16 + quad * 4 + r];

  // ---------------- pass 2: weights out + PV ----------------
  float* awp = attw + ((size_t)bh * 2048 + q0) * 2048;
  f32x4 oacc[2][4] = {};
  u16x8 kq0 = *(const u16x8*)(Kb + (size_t)sr0 * 1024 + sc0);
  u16x8 kq1 = *(const u16x8*)(Kb + (size_t)sr1 * 1024 + sc0);
  u16x8 vq0 = *(const u16x8*)(Vb + (size_t)sr0 * 2048 + sc0);
  u16x8 vq1 = *(const u16x8*)(Vb + (size_t)sr1 * 2048 + sc0);
  for (int kt = 0; kt < 2048; kt += 64) {
    __syncthreads();                       // prev tile's Ks/Vs readers done
    *(u16x8*)&Ks[sr0][sc0] = kq0;
    *(u16x8*)&Ks[sr1][sc0] = kq1;
    *(u16x8*)&Vs[sr0][sc0] = vq0;
    *(u16x8*)&Vs[sr1][sc0] = vq1;
    __syncthreads();
    if (kt + 64 < 2048) {                  // prefetch next K+V tiles into regs
      kq0 = *(const u16x8*)(Kb + (size_t)(kt + 64 + sr0) * 1024 + sc0);
      kq1 = *(const u16x8*)(Kb + (size_t)(kt + 64 + sr1) * 1024 + sc0);
      vq0 = *(const u16x8*)(Vb + (size_t)sr0 * 2048 + kt + 64 + sc0);
      vq1 = *(const u16x8*)(Vb + (size_t)sr1 * 2048 + kt + 64 + sc0);
    }
    f32x4 acc[2][4] = {};
#pragma unroll
    for (int ks = 0; ks < 2; ks++) {
      bf16x8 bg[4];
#pragma unroll
      for (int j = 0; j < 4; j++)
        bg[j] = *(const bf16x8*)&Ks[j * 16 + l16][ks * 32 + quad * 8];
#pragma unroll
      for (int i = 0; i < 2; i++)
#pragma unroll
        for (int j = 0; j < 4; j++)
          acc[i][j] = __builtin_amdgcn_mfma_f32_16x16x32_bf16(qf[i][ks], bg[j], acc[i][j], 0, 0, 0);
    }
    // w = exp(s)/l : fp32 to HBM (mandatory 1.07GB), bf16 to Ws (QW rows are
    // wave-private: rows wave*32..wave*32+31 written AND read by this wave only)
#pragma unroll
    for (int i = 0; i < 2; i++)
#pragma unroll
      for (int j = 0; j < 4; j++) {
        int colg = kt + j * 16 + l16;
#pragma unroll
        for (int r = 0; r < 4; r++) {
          int rowl = wave * 32 + i * 16 + quad * 4 + r;
          float w = __expf(acc[i][j][r] * scale) * linv[i][r];
          awp[(size_t)rowl * 2048 + colg] = w;
          QW[rowl][j * 16 + l16] = f2bf(w);
        }
      }
    asm volatile("s_waitcnt lgkmcnt(0)" ::: "memory");   // wave-local Ws visibility
    // PV: O[q][d] += Ws[q][kk] * Vs[d][kk]^T
#pragma unroll
    for (int ks = 0; ks < 2; ks++) {
      bf16x8 af[2], bg[4];
#pragma unroll
      for (int i = 0; i < 2; i++)
        af[i] = *(const bf16x8*)&QW[wave * 32 + i * 16 + l16][ks * 32 + quad * 8];
#pragma unroll
      for (int j = 0; j < 4; j++)
        bg[j] = *(const bf16x8*)&Vs[j * 16 + l16][ks * 32 + quad * 8];
#pragma unroll
      for (int i = 0; i < 2; i++)
#pragma unroll
        for (int j = 0; j < 4; j++)
          oacc[i][j] = __builtin_amdgcn_mfma_f32_16x16x32_bf16(af[i], bg[j], oacc[i][j], 0, 0, 0);
    }
  }

  // epilogue: AO[b*2048+q][h*64+d] bf16  (heads re-interleaved for final GEMM)
#pragma unroll
  for (int i = 0; i < 2; i++)
#pragma unroll
    for (int j = 0; j < 4; j++) {
      int d = j * 16 + l16;
#pragma unroll
      for (int r = 0; r < 4; r++) {
        int rowl = wave * 32 + i * 16 + quad * 4 + r;
        AO[(size_t)(b * 2048 + q0 + rowl) * 1024 + h * 64 + d] = f2bf(oacc[i][j][r]);
      }
    }
}

// ---------------------------------------------------------------------------
extern "C" void kernel_launch(void* const* d_in, const int* in_sizes, int n_in,
                              void* d_out, int out_size, void* d_ws, size_t ws_size,
                              hipStream_t stream) {
  const float* query = (const float*)d_in[0];
  const float* key   = (const float*)d_in[1];
  const float* value = (const float*)d_in[2];
  const float* Wq = (const float*)d_in[3];
  const float* bq = (const float*)d_in[4];
  const float* Wk = (const float*)d_in[5];
  const float* bk = (const float*)d_in[6];
  const float* Wv = (const float*)d_in[7];
  const float* bv = (const float*)d_in[8];
  const float* Wo = (const float*)d_in[9];
  const float* bo = (const float*)d_in[10];

  float* out  = (float*)d_out;                       // [4,2048,1024] fp32 (33.5MB)
  float* attw = out + (size_t)8192 * 1024;           // [4,16,2048,2048] fp32

  // workspace layout (83.9 MiB, same as proven-previous session)
  u16* Qp = (u16*)d_ws;                              // [8192][1024] bf16
  u16* Kp = Qp + (size_t)8192 * 1024;
  u16* Vp = Kp + (size_t)8192 * 1024;
  u16* Vt = Vp + (size_t)8192 * 1024;                // [64][64][2048] bf16
  u16* AO = Vt + (size_t)64 * 64 * 2048;             // [8192][1024] bf16

  // scratch inside the (not-yet-written) `out` region of d_out:
  //   Xb  = converted activation input (16.8MB), Wq/Wk/Wv bf16 (2.1MB each).
  // All are dead before the final GEMM overwrites `out`.
  u16* Xb  = (u16*)out;                              // [8192][1024] bf16
  u16* Wqb = Xb + (size_t)8192 * 1024;
  u16* Wkb = Wqb + (size_t)1024 * 1024;
  u16* Wvb = Wkb + (size_t)1024 * 1024;              // ends at 23.1MB < 33.5MB
  u16* Wob = Qp;                                     // Qp region dead after attn

  dim3 blk(256);
  dim3 gg(8, 64);     // N/128, M/128
  const int nA8 = 8192 * 1024 / 8, nW8 = 1024 * 1024 / 8;
  const int gA = 2048, gW = nW8 / 256;               // grid-stride for A converts

  cvt_bf16<<<dim3(gW), blk, 0, stream>>>(Wq, Wqb, nW8);
  cvt_bf16<<<dim3(gW), blk, 0, stream>>>(Wk, Wkb, nW8);
  cvt_bf16<<<dim3(gW), blk, 0, stream>>>(Wv, Wvb, nW8);

  cvt_bf16<<<dim3(gA), blk, 0, stream>>>(query, Xb, nA8);
  gemm_bt<false><<<gg, blk, 0, stream>>>(Xb, Wqb, bq, Qp);
  cvt_bf16<<<dim3(gA), blk, 0, stream>>>(key, Xb, nA8);
  gemm_bt<false><<<gg, blk, 0, stream>>>(Xb, Wkb, bk, Kp);
  cvt_bf16<<<dim3(gA), blk, 0, stream>>>(value, Xb, nA8);
  gemm_bt<false><<<gg, blk, 0, stream>>>(Xb, Wvb, bv, Vp);

  transpose_v<<<dim3(32, 64), blk, 0, stream>>>(Vp, Vt);
  attn<<<dim3(1024), blk, 0, stream>>>(Qp, Kp, Vt, attw, AO);

  cvt_bf16<<<dim3(gW), blk, 0, stream>>>(Wo, Wob, nW8);  // into dead Qp region
  gemm_bt<true><<<gg, blk, 0, stream>>>(AO, Wob, bo, (void*)out);
}